// Round 2
// baseline (636.596 us; speedup 1.0000x reference)
//
#include <hip/hip_runtime.h>
#include <hip/hip_bf16.h>
#include <math.h>

typedef unsigned short ushort_t;
typedef short short8 __attribute__((ext_vector_type(8)));
typedef float f32x4 __attribute__((ext_vector_type(4)));

#define N_TOK 512
#define EMBED 1024
#define INTER 4096
#define NCAT  5120   /* INTER + EMBED */
#define MROWS 24576  /* 48 * 512 */

__device__ __forceinline__ ushort_t f2bf(float f) {
  union { float f; unsigned int u; } c; c.f = f;
  unsigned int u = c.u;
  unsigned int r = u + 0x7fffu + ((u >> 16) & 1u);
  return (ushort_t)(r >> 16);
}

__device__ __forceinline__ void gld_lds16(const void* g, void* l) {
  __builtin_amdgcn_global_load_lds(
      (const __attribute__((address_space(1))) void*)g,
      (__attribute__((address_space(3))) void*)l, 16, 0, 0);
}

// ---- prep kernels -------------------------------------------------------

__global__ void prep_bcat(const float* __restrict__ bl, const float* __restrict__ br,
                          float* __restrict__ dst) {
  int i = blockIdx.x * 256 + threadIdx.x;
  if (i >= NCAT) return;
  dst[i] = (i < INTER) ? bl[i] : br[i - INTER];
}

__global__ void prep_wout(const float* __restrict__ W, ushort_t* __restrict__ dst) {
  int i = blockIdx.x * 256 + threadIdx.x;   // total EMBED*INTER, exact grid
  dst[i] = f2bf(W[i]);
}

// interp columns of [Wl;Wr] (96 -> P3), zero-pad to Kpad, bf16
__global__ void prep_wcat(const float* __restrict__ Wl, const float* __restrict__ Wr,
                          ushort_t* __restrict__ dst, int P3, int Kpad) {
  int i = blockIdx.x * 256 + threadIdx.x;
  int total = NCAT * Kpad;
  if (i >= total) return;
  int r = i / Kpad, j = i - r * Kpad;
  float v = 0.f;
  if (j < P3) {
    float scale = 96.0f / (float)P3;
    float src = (j + 0.5f) * scale - 0.5f;
    src = fminf(fmaxf(src, 0.0f), 95.0f);
    int i0 = (int)src;
    int i1 = min(i0 + 1, 95);
    float tt = src - (float)i0;
    const float* Wrow = (r < INTER) ? (Wl + (size_t)r * 96)
                                    : (Wr + (size_t)(r - INTER) * 96);
    v = Wrow[i0] * (1.f - tt) + Wrow[i1] * tt;
  }
  dst[i] = f2bf(v);
}

// xs = [x|m|t] -> bf16, zero-pad to Kpad. rows = 8192 (16 layers * 512 tok)
__global__ void prep_xs(const float* __restrict__ x, const float* __restrict__ m,
                        const float* __restrict__ t, ushort_t* __restrict__ dst,
                        int p, int Kpad) {
  int i = blockIdx.x * 256 + threadIdx.x;
  int total = 8192 * Kpad;
  if (i >= total) return;
  int r = i / Kpad, j = i - r * Kpad;
  float v = 0.f;
  int p3 = 3 * p;
  if (j < p3) {
    size_t base = (size_t)r * p;
    if (j < p)           v = x[base + j];
    else if (j < 2 * p)  v = m[base + j - p];
    else                 v = t[base + j - 2 * p];
  }
  dst[i] = f2bf(v);
}

// ---- 128x128 bf16 MFMA GEMM, fragment-ordered LDS staging --------------
// A: [M][Kpad] bf16 row-major; B: [N][Kpad] bf16 row-major (i.e. B^T);
// C[m][n] = sum_k A[m][k]*B[n][k]
// LDS layout: 8 subtiles per operand per K-step, each 16 rows x 32 cols
// stored in MFMA fragment order (lane l: row l&15, cols (l>>4)*8..+7 at
// byte l*16). global_load_lds writes linearly (base + lane*16), so the
// per-lane GLOBAL address carries the permutation (m173 pattern). All
// ds_read_b128 then hit base + lane*16 -> zero bank conflicts.
// MODE 0: phase-1. cols<INTER -> hidden = bf16(silu(acc+bias)); cols>=INTER
//         -> d_out = acc+bias (f32). Rows scattered by idxg (layer perm).
// MODE 1: phase-2. d_out += acc + bias.
template <int MODE>
__global__ __launch_bounds__(256)
void gemm128(const ushort_t* __restrict__ A, const ushort_t* __restrict__ B,
             int Kpad, const float* __restrict__ bias,
             ushort_t* __restrict__ hidden, float* __restrict__ outp,
             const int* __restrict__ idxg) {
  __shared__ __align__(16) ushort_t lA[128 * 32];
  __shared__ __align__(16) ushort_t lB[128 * 32];
  const int t = threadIdx.x;
  const int wave = t >> 6, lane = t & 63;
  const int tm = blockIdx.x * 128, tn = blockIdx.y * 128;

  // fragment coords for staging: lane l covers (row fr, cols fc..fc+7)
  const int fr = lane & 15;
  const int fc = (lane >> 4) * 8;
  // wave w stages A subtiles 2w,2w+1 and B subtiles 2w,2w+1
  const int s0 = wave * 2;
  const ushort_t* gA0 = A + (size_t)(tm + s0 * 16 + fr) * Kpad + fc;
  const ushort_t* gA1 = gA0 + (size_t)16 * Kpad;
  const ushort_t* gB0 = B + (size_t)(tn + s0 * 16 + fr) * Kpad + fc;
  const ushort_t* gB1 = gB0 + (size_t)16 * Kpad;
  ushort_t* lA0 = lA + s0 * 512;   // subtile = 1024 B = 512 ushort
  ushort_t* lA1 = lA0 + 512;
  ushort_t* lB0 = lB + s0 * 512;
  ushort_t* lB1 = lB0 + 512;

  const int wr = wave >> 1, wc = wave & 1;
  const f32x4 zero = {0.f, 0.f, 0.f, 0.f};
  f32x4 acc[4][4];
#pragma unroll
  for (int m2 = 0; m2 < 4; ++m2)
#pragma unroll
    for (int n2 = 0; n2 < 4; ++n2) acc[m2][n2] = zero;

  // fragment read pointers: subtile base + lane*16B (conflict-free)
  const ushort_t* pa = lA + (wr * 4) * 512 + lane * 8;
  const ushort_t* pb = lB + (wc * 4) * 512 + lane * 8;

  for (int kk = 0; kk < Kpad; kk += 32) {
    gld_lds16(gA0, lA0); gld_lds16(gA1, lA1);
    gld_lds16(gB0, lB0); gld_lds16(gB1, lB1);
    gA0 += 32; gA1 += 32; gB0 += 32; gB1 += 32;
    __syncthreads();
    short8 aF[4], bF[4];
#pragma unroll
    for (int m2 = 0; m2 < 4; ++m2) aF[m2] = *(const short8*)(pa + m2 * 512);
#pragma unroll
    for (int n2 = 0; n2 < 4; ++n2) bF[n2] = *(const short8*)(pb + n2 * 512);
#pragma unroll
    for (int m2 = 0; m2 < 4; ++m2)
#pragma unroll
      for (int n2 = 0; n2 < 4; ++n2)
        acc[m2][n2] = __builtin_amdgcn_mfma_f32_16x16x32_bf16(
            aF[m2], bF[n2], acc[m2][n2], 0, 0, 0);
    __syncthreads();
  }

  int rowBase;
  if (MODE == 0) {
    const int layer = idxg[tm >> 9];          // 128-row tile stays in one layer
    rowBase = layer * N_TOK + (tm & (N_TOK - 1));
  } else {
    rowBase = tm;
  }

#pragma unroll
  for (int m2 = 0; m2 < 4; ++m2) {
#pragma unroll
    for (int n2 = 0; n2 < 4; ++n2) {
      const int colg = tn + wc * 64 + n2 * 16 + (lane & 15);
      const float bv = bias[colg];
#pragma unroll
      for (int r = 0; r < 4; ++r) {
        const int rowl = wr * 64 + m2 * 16 + (lane >> 4) * 4 + r;
        const float v = acc[m2][n2][r];
        if (MODE == 0) {
          const int grow = rowBase + rowl;
          if (colg < INTER) {
            float h = v + bv;
            h = h / (1.f + expf(-h));
            hidden[(size_t)grow * INTER + colg] = f2bf(h);
          } else {
            outp[(size_t)grow * EMBED + (colg - INTER)] = v + bv;
          }
        } else {
          float* po = outp + (size_t)(tm + rowl) * EMBED + colg;
          *po += v + bv;
        }
      }
    }
  }
}

// ---- launch -------------------------------------------------------------

extern "C" void kernel_launch(void* const* d_in, const int* in_sizes, int n_in,
                              void* d_out, int out_size, void* d_ws, size_t ws_size,
                              hipStream_t stream) {
  const float* xg[3] = {(const float*)d_in[0], (const float*)d_in[3], (const float*)d_in[6]};
  const float* mg[3] = {(const float*)d_in[1], (const float*)d_in[4], (const float*)d_in[7]};
  const float* tg[3] = {(const float*)d_in[2], (const float*)d_in[5], (const float*)d_in[8]};
  const int* idxg[3] = {(const int*)d_in[9], (const int*)d_in[10], (const int*)d_in[11]};
  const float* W_lin = (const float*)d_in[12];
  const float* b_lin = (const float*)d_in[13];
  const float* W_res = (const float*)d_in[14];
  const float* b_res = (const float*)d_in[15];
  const float* W_out = (const float*)d_in[16];
  const float* b_out = (const float*)d_in[17];
  float* out = (float*)d_out;

  char* ws = (char*)d_ws;
  size_t off = 0;
  auto alloc = [&](size_t b) -> char* {
    size_t o = (off + 255) & ~(size_t)255;
    off = o + b;
    return ws + o;
  };

  ushort_t* hidden = (ushort_t*)alloc((size_t)MROWS * INTER * 2);   // 201 MB
  const int Ps[3] = {16, 32, 64};
  const int Kp[3] = {64, 96, 192};
  ushort_t* xsw[3];
  ushort_t* wcat[3];
  for (int g = 0; g < 3; ++g) xsw[g]  = (ushort_t*)alloc((size_t)8192 * Kp[g] * 2);
  for (int g = 0; g < 3; ++g) wcat[g] = (ushort_t*)alloc((size_t)NCAT * Kp[g] * 2);
  ushort_t* wout = (ushort_t*)alloc((size_t)EMBED * INTER * 2);     // 8 MB
  float* bcat = (float*)alloc((size_t)NCAT * 4);

  prep_bcat<<<(NCAT + 255) / 256, 256, 0, stream>>>(b_lin, b_res, bcat);
  prep_wout<<<(EMBED * INTER) / 256, 256, 0, stream>>>(W_out, wout);
  for (int g = 0; g < 3; ++g) {
    int tw = NCAT * Kp[g];
    prep_wcat<<<(tw + 255) / 256, 256, 0, stream>>>(W_lin, W_res, wcat[g], 3 * Ps[g], Kp[g]);
    int tx = 8192 * Kp[g];
    prep_xs<<<(tx + 255) / 256, 256, 0, stream>>>(xg[g], mg[g], tg[g], xsw[g], Ps[g], Kp[g]);
  }
  // phase 1: per group, [8192 x Kp] @ [5120 x Kp]^T
  for (int g = 0; g < 3; ++g)
    gemm128<0><<<dim3(64, 40), 256, 0, stream>>>(xsw[g], wcat[g], Kp[g], bcat,
                                                 hidden, out, idxg[g]);
  // phase 2: [24576 x 4096] @ [1024 x 4096]^T, += into out
  gemm128<1><<<dim3(192, 8), 256, 0, stream>>>(hidden, wout, INTER, b_out,
                                               nullptr, out, nullptr);
}

// Round 3
// 498.470 us; speedup vs baseline: 1.2771x; 1.2771x over previous
//
#include <hip/hip_runtime.h>
#include <hip/hip_bf16.h>
#include <math.h>

typedef unsigned short ushort_t;
typedef short short8 __attribute__((ext_vector_type(8)));
typedef float f32x4 __attribute__((ext_vector_type(4)));

#define N_TOK 512
#define EMBED 1024
#define INTER 4096
#define NCAT  5120   /* INTER + EMBED */
#define MROWS 24576  /* 48 * 512 */

__device__ __forceinline__ ushort_t f2bf(float f) {
  union { float f; unsigned int u; } c; c.f = f;
  unsigned int u = c.u;
  unsigned int r = u + 0x7fffu + ((u >> 16) & 1u);
  return (ushort_t)(r >> 16);
}

__device__ __forceinline__ void gld_lds16(const void* g, void* l) {
  __builtin_amdgcn_global_load_lds(
      (const __attribute__((address_space(1))) void*)g,
      (__attribute__((address_space(3))) void*)l, 16, 0, 0);
}

// ---- prep kernels -------------------------------------------------------

__global__ void prep_bcat(const float* __restrict__ bl, const float* __restrict__ br,
                          float* __restrict__ dst) {
  int i = blockIdx.x * 256 + threadIdx.x;
  if (i >= NCAT) return;
  dst[i] = (i < INTER) ? bl[i] : br[i - INTER];
}

__global__ void prep_wout(const float* __restrict__ W, ushort_t* __restrict__ dst) {
  int i = blockIdx.x * 256 + threadIdx.x;   // total EMBED*INTER, exact grid
  dst[i] = f2bf(W[i]);
}

// interp columns of [Wl;Wr] (96 -> P3), zero-pad to Kpad, bf16
__global__ void prep_wcat(const float* __restrict__ Wl, const float* __restrict__ Wr,
                          ushort_t* __restrict__ dst, int P3, int Kpad) {
  int i = blockIdx.x * 256 + threadIdx.x;
  int total = NCAT * Kpad;
  if (i >= total) return;
  int r = i / Kpad, j = i - r * Kpad;
  float v = 0.f;
  if (j < P3) {
    float scale = 96.0f / (float)P3;
    float src = (j + 0.5f) * scale - 0.5f;
    src = fminf(fmaxf(src, 0.0f), 95.0f);
    int i0 = (int)src;
    int i1 = min(i0 + 1, 95);
    float tt = src - (float)i0;
    const float* Wrow = (r < INTER) ? (Wl + (size_t)r * 96)
                                    : (Wr + (size_t)(r - INTER) * 96);
    v = Wrow[i0] * (1.f - tt) + Wrow[i1] * tt;
  }
  dst[i] = f2bf(v);
}

// xs = [x|m|t] -> bf16, zero-pad to Kpad. rows = 8192 (16 layers * 512 tok)
__global__ void prep_xs(const float* __restrict__ x, const float* __restrict__ m,
                        const float* __restrict__ t, ushort_t* __restrict__ dst,
                        int p, int Kpad) {
  int i = blockIdx.x * 256 + threadIdx.x;
  int total = 8192 * Kpad;
  if (i >= total) return;
  int r = i / Kpad, j = i - r * Kpad;
  float v = 0.f;
  int p3 = 3 * p;
  if (j < p3) {
    size_t base = (size_t)r * p;
    if (j < p)           v = x[base + j];
    else if (j < 2 * p)  v = m[base + j - p];
    else                 v = t[base + j - 2 * p];
  }
  dst[i] = f2bf(v);
}

// ---- 128x128 bf16 MFMA GEMM -------------------------------------------
// T2 both-sides XOR swizzle + T3-min 2-phase pipeline (ping-pong LDS,
// prefetch-before-compute, counted vmcnt, raw s_barrier).
//
// LDS tile per operand per buffer: row-major [128 rows][32 ushort = 64B],
// with 16B chunks XOR-permuted within each row: content(row, pos) =
// global chunk (pos ^ ((row>>1)&3)). Stage quads still read one 64B line
// per row (coalesced); fragment ds_read_b128 is bank-balanced (32B/bank).
//
// A: [M][Kpad] bf16 row-major; B: [N][Kpad] bf16 row-major (i.e. B^T);
// C[m][n] = sum_k A[m][k]*B[n][k]
// MODE 0: phase-1. cols<INTER -> hidden = bf16(silu(acc+bias)); cols>=INTER
//         -> d_out = acc+bias (f32). Rows scattered by idxg (layer perm).
// MODE 1: phase-2. d_out += acc + bias. 1-D grid with XCD-aware remap.
template <int MODE>
__global__ __launch_bounds__(256)
void gemm128(const ushort_t* __restrict__ A, const ushort_t* __restrict__ B,
             int Kpad, const float* __restrict__ bias,
             ushort_t* __restrict__ hidden, float* __restrict__ outp,
             const int* __restrict__ idxg) {
  __shared__ __align__(16) ushort_t lA[2][128 * 32];
  __shared__ __align__(16) ushort_t lB[2][128 * 32];
  const int t = threadIdx.x;
  const int wave = t >> 6, lane = t & 63;

  int tm, tn;
  if (MODE == 1) {
    // XCD-aware remap: 1536 blocks; xcd = L%8 owns slabs [24*xcd, 24*xcd+24),
    // iterating the 8 column-tiles of a slab consecutively (A-slab L2 reuse).
    const int L = blockIdx.x;
    const int xcd = L & 7, j = L >> 3;          // j in [0,192)
    tm = (xcd * 24 + (j >> 3)) * 128;
    tn = (j & 7) * 128;
  } else {
    tm = blockIdx.x * 128;
    tn = blockIdx.y * 128;
  }

  // ---- staging addressing (quad-coalesced, source-side XOR) ----
  // wave w stages chunks 2w, 2w+1 (16 rows x 64B each) of A and B.
  const int chunk = wave * 2;
  const int srow = chunk * 16 + (lane >> 2);            // global row in tile
  const int scol = (((lane & 3) ^ ((lane >> 3) & 3)) * 8); // XOR'd 16B chunk
  const ushort_t* gA0 = A + (size_t)(tm + srow) * Kpad + scol;
  const ushort_t* gA1 = gA0 + (size_t)16 * Kpad;
  const ushort_t* gB0 = B + (size_t)(tn + srow) * Kpad + scol;
  const ushort_t* gB1 = gB0 + (size_t)16 * Kpad;
  const int ldsOff0 = chunk * 512;                      // 1024B subtiles
  const int ldsOff1 = ldsOff0 + 512;

  const int wr = wave >> 1, wc = wave & 1;
  const f32x4 zero = {0.f, 0.f, 0.f, 0.f};
  f32x4 acc[4][4];
#pragma unroll
  for (int m2 = 0; m2 < 4; ++m2)
#pragma unroll
    for (int n2 = 0; n2 < 4; ++n2) acc[m2][n2] = zero;

  // ---- fragment read addressing (read-side XOR, bank-balanced) ----
  const int xf = ((lane & 15) >> 1) & 3;                // per-lane constant
  const int fcol = (((lane >> 4) ^ xf)) * 8;
  const int aoff = (wr * 64 + (lane & 15)) * 32 + fcol;
  const int boff = (wc * 64 + (lane & 15)) * 32 + fcol;

  const int nk = Kpad >> 5;

  // prologue: stage tile 0 into buffer 0
  {
    gld_lds16(gA0, &lA[0][ldsOff0]); gld_lds16(gA1, &lA[0][ldsOff1]);
    gld_lds16(gB0, &lB[0][ldsOff0]); gld_lds16(gB1, &lB[0][ldsOff1]);
    gA0 += 32; gA1 += 32; gB0 += 32; gB1 += 32;
  }

  for (int kk = 0; kk < nk; ++kk) {
    const int cur = kk & 1;
    if (kk + 1 < nk) {
      const int nxt = cur ^ 1;
      gld_lds16(gA0, &lA[nxt][ldsOff0]); gld_lds16(gA1, &lA[nxt][ldsOff1]);
      gld_lds16(gB0, &lB[nxt][ldsOff0]); gld_lds16(gB1, &lB[nxt][ldsOff1]);
      gA0 += 32; gA1 += 32; gB0 += 32; gB1 += 32;
      asm volatile("s_waitcnt vmcnt(4)" ::: "memory");  // tile kk landed (mine)
    } else {
      asm volatile("s_waitcnt vmcnt(0)" ::: "memory");
    }
    __builtin_amdgcn_s_barrier();                       // everyone's landed

    const ushort_t* pa = &lA[cur][0] + aoff;
    const ushort_t* pb = &lB[cur][0] + boff;
    short8 aF[4], bF[4];
#pragma unroll
    for (int m2 = 0; m2 < 4; ++m2) aF[m2] = *(const short8*)(pa + m2 * 16 * 32);
#pragma unroll
    for (int n2 = 0; n2 < 4; ++n2) bF[n2] = *(const short8*)(pb + n2 * 16 * 32);
#pragma unroll
    for (int m2 = 0; m2 < 4; ++m2)
#pragma unroll
      for (int n2 = 0; n2 < 4; ++n2)
        acc[m2][n2] = __builtin_amdgcn_mfma_f32_16x16x32_bf16(
            aF[m2], bF[n2], acc[m2][n2], 0, 0, 0);
    __builtin_amdgcn_s_barrier();   // all reads of `cur` done before overwrite
  }

  int rowBase;
  if (MODE == 0) {
    const int layer = idxg[tm >> 9];          // 128-row tile stays in one layer
    rowBase = layer * N_TOK + (tm & (N_TOK - 1));
  } else {
    rowBase = tm;
  }

#pragma unroll
  for (int m2 = 0; m2 < 4; ++m2) {
#pragma unroll
    for (int n2 = 0; n2 < 4; ++n2) {
      const int colg = tn + wc * 64 + n2 * 16 + (lane & 15);
      const float bv = bias[colg];
#pragma unroll
      for (int r = 0; r < 4; ++r) {
        const int rowl = wr * 64 + m2 * 16 + (lane >> 4) * 4 + r;
        const float v = acc[m2][n2][r];
        if (MODE == 0) {
          const int grow = rowBase + rowl;
          if (colg < INTER) {
            float h = v + bv;
            h = h / (1.f + expf(-h));
            hidden[(size_t)grow * INTER + colg] = f2bf(h);
          } else {
            outp[(size_t)grow * EMBED + (colg - INTER)] = v + bv;
          }
        } else {
          float* po = outp + (size_t)(rowBase + rowl) * EMBED + colg;
          *po += v + bv;
        }
      }
    }
  }
}

// ---- launch -------------------------------------------------------------

extern "C" void kernel_launch(void* const* d_in, const int* in_sizes, int n_in,
                              void* d_out, int out_size, void* d_ws, size_t ws_size,
                              hipStream_t stream) {
  const float* xg[3] = {(const float*)d_in[0], (const float*)d_in[3], (const float*)d_in[6]};
  const float* mg[3] = {(const float*)d_in[1], (const float*)d_in[4], (const float*)d_in[7]};
  const float* tg[3] = {(const float*)d_in[2], (const float*)d_in[5], (const float*)d_in[8]};
  const int* idxg[3] = {(const int*)d_in[9], (const int*)d_in[10], (const int*)d_in[11]};
  const float* W_lin = (const float*)d_in[12];
  const float* b_lin = (const float*)d_in[13];
  const float* W_res = (const float*)d_in[14];
  const float* b_res = (const float*)d_in[15];
  const float* W_out = (const float*)d_in[16];
  const float* b_out = (const float*)d_in[17];
  float* out = (float*)d_out;

  char* ws = (char*)d_ws;
  size_t off = 0;
  auto alloc = [&](size_t b) -> char* {
    size_t o = (off + 255) & ~(size_t)255;
    off = o + b;
    return ws + o;
  };

  ushort_t* hidden = (ushort_t*)alloc((size_t)MROWS * INTER * 2);   // 201 MB
  const int Ps[3] = {16, 32, 64};
  const int Kp[3] = {64, 96, 192};
  ushort_t* xsw[3];
  ushort_t* wcat[3];
  for (int g = 0; g < 3; ++g) xsw[g]  = (ushort_t*)alloc((size_t)8192 * Kp[g] * 2);
  for (int g = 0; g < 3; ++g) wcat[g] = (ushort_t*)alloc((size_t)NCAT * Kp[g] * 2);
  ushort_t* wout = (ushort_t*)alloc((size_t)EMBED * INTER * 2);     // 8 MB
  float* bcat = (float*)alloc((size_t)NCAT * 4);

  prep_bcat<<<(NCAT + 255) / 256, 256, 0, stream>>>(b_lin, b_res, bcat);
  prep_wout<<<(EMBED * INTER) / 256, 256, 0, stream>>>(W_out, wout);
  for (int g = 0; g < 3; ++g) {
    int tw = NCAT * Kp[g];
    prep_wcat<<<(tw + 255) / 256, 256, 0, stream>>>(W_lin, W_res, wcat[g], 3 * Ps[g], Kp[g]);
    int tx = 8192 * Kp[g];
    prep_xs<<<(tx + 255) / 256, 256, 0, stream>>>(xg[g], mg[g], tg[g], xsw[g], Ps[g], Kp[g]);
  }
  // phase 1: per group, [8192 x Kp] @ [5120 x Kp]^T
  for (int g = 0; g < 3; ++g)
    gemm128<0><<<dim3(64, 40), 256, 0, stream>>>(xsw[g], wcat[g], Kp[g], bcat,
                                                 hidden, out, idxg[g]);
  // phase 2: [24576 x 4096] @ [1024 x 4096]^T, += into out (XCD-swizzled 1-D grid)
  gemm128<1><<<dim3(1536), 256, 0, stream>>>(hidden, wout, INTER, b_out,
                                             nullptr, out, nullptr);
}

// Round 5
// 464.993 us; speedup vs baseline: 1.3690x; 1.0720x over previous
//
#include <hip/hip_runtime.h>
#include <hip/hip_bf16.h>
#include <math.h>

typedef unsigned short ushort_t;
typedef short short8 __attribute__((ext_vector_type(8)));
typedef float f32x4 __attribute__((ext_vector_type(4)));

#define N_TOK 512
#define EMBED 1024
#define INTER 4096
#define NCAT  5120   /* INTER + EMBED */
#define MROWS 24576  /* 48 * 512 */

__device__ __forceinline__ ushort_t f2bf(float f) {
  union { float f; unsigned int u; } c; c.f = f;
  unsigned int u = c.u;
  unsigned int r = u + 0x7fffu + ((u >> 16) & 1u);
  return (ushort_t)(r >> 16);
}

__device__ __forceinline__ void gld_lds16(const void* g, void* l) {
  __builtin_amdgcn_global_load_lds(
      (const __attribute__((address_space(1))) void*)g,
      (__attribute__((address_space(3))) void*)l, 16, 0, 0);
}

// ---- prep kernels -------------------------------------------------------

__global__ void prep_bcat(const float* __restrict__ bl, const float* __restrict__ br,
                          float* __restrict__ dst) {
  int i = blockIdx.x * 256 + threadIdx.x;
  if (i >= NCAT) return;
  dst[i] = (i < INTER) ? bl[i] : br[i - INTER];
}

__global__ void prep_wout(const float* __restrict__ W, ushort_t* __restrict__ dst) {
  int i = blockIdx.x * 256 + threadIdx.x;   // total EMBED*INTER, exact grid
  dst[i] = f2bf(W[i]);
}

__global__ void prep_wcat(const float* __restrict__ Wl, const float* __restrict__ Wr,
                          ushort_t* __restrict__ dst, int P3, int Kpad) {
  int i = blockIdx.x * 256 + threadIdx.x;
  int total = NCAT * Kpad;
  if (i >= total) return;
  int r = i / Kpad, j = i - r * Kpad;
  float v = 0.f;
  if (j < P3) {
    float scale = 96.0f / (float)P3;
    float src = (j + 0.5f) * scale - 0.5f;
    src = fminf(fmaxf(src, 0.0f), 95.0f);
    int i0 = (int)src;
    int i1 = min(i0 + 1, 95);
    float tt = src - (float)i0;
    const float* Wrow = (r < INTER) ? (Wl + (size_t)r * 96)
                                    : (Wr + (size_t)(r - INTER) * 96);
    v = Wrow[i0] * (1.f - tt) + Wrow[i1] * tt;
  }
  dst[i] = f2bf(v);
}

__global__ void prep_xs(const float* __restrict__ x, const float* __restrict__ m,
                        const float* __restrict__ t, ushort_t* __restrict__ dst,
                        int p, int Kpad) {
  int i = blockIdx.x * 256 + threadIdx.x;
  int total = 8192 * Kpad;
  if (i >= total) return;
  int r = i / Kpad, j = i - r * Kpad;
  float v = 0.f;
  int p3 = 3 * p;
  if (j < p3) {
    size_t base = (size_t)r * p;
    if (j < p)           v = x[base + j];
    else if (j < 2 * p)  v = m[base + j - p];
    else                 v = t[base + j - 2 * p];
  }
  dst[i] = f2bf(v);
}

// ---- phase-1: 128x128 GEMM (R3 structure, proven) -----------------------
__global__ __launch_bounds__(256)
void gemm128p1(const ushort_t* __restrict__ A, const ushort_t* __restrict__ B,
               int Kpad, const float* __restrict__ bias,
               ushort_t* __restrict__ hidden, float* __restrict__ outp,
               const int* __restrict__ idxg) {
  __shared__ __align__(16) ushort_t lA[2][128 * 32];
  __shared__ __align__(16) ushort_t lB[2][128 * 32];
  const int t = threadIdx.x;
  const int wave = t >> 6, lane = t & 63;
  const int tm = blockIdx.x * 128, tn = blockIdx.y * 128;

  const int chunk = wave * 2;
  const int srow = chunk * 16 + (lane >> 2);
  const int scol = (((lane & 3) ^ ((lane >> 3) & 3)) * 8);
  const ushort_t* gA0 = A + (size_t)(tm + srow) * Kpad + scol;
  const ushort_t* gA1 = gA0 + (size_t)16 * Kpad;
  const ushort_t* gB0 = B + (size_t)(tn + srow) * Kpad + scol;
  const ushort_t* gB1 = gB0 + (size_t)16 * Kpad;
  const int ldsOff0 = chunk * 512;
  const int ldsOff1 = ldsOff0 + 512;

  const int wr = wave >> 1, wc = wave & 1;
  const f32x4 zero = {0.f, 0.f, 0.f, 0.f};
  f32x4 acc[4][4];
#pragma unroll
  for (int m2 = 0; m2 < 4; ++m2)
#pragma unroll
    for (int n2 = 0; n2 < 4; ++n2) acc[m2][n2] = zero;

  const int xf = ((lane & 15) >> 1) & 3;
  const int fcol = (((lane >> 4) ^ xf)) * 8;
  const int aoff = (wr * 64 + (lane & 15)) * 32 + fcol;
  const int boff = (wc * 64 + (lane & 15)) * 32 + fcol;

  const int nk = Kpad >> 5;
  gld_lds16(gA0, &lA[0][ldsOff0]); gld_lds16(gA1, &lA[0][ldsOff1]);
  gld_lds16(gB0, &lB[0][ldsOff0]); gld_lds16(gB1, &lB[0][ldsOff1]);
  gA0 += 32; gA1 += 32; gB0 += 32; gB1 += 32;

  for (int kk = 0; kk < nk; ++kk) {
    const int cur = kk & 1;
    if (kk + 1 < nk) {
      const int nxt = cur ^ 1;
      gld_lds16(gA0, &lA[nxt][ldsOff0]); gld_lds16(gA1, &lA[nxt][ldsOff1]);
      gld_lds16(gB0, &lB[nxt][ldsOff0]); gld_lds16(gB1, &lB[nxt][ldsOff1]);
      gA0 += 32; gA1 += 32; gB0 += 32; gB1 += 32;
      asm volatile("s_waitcnt vmcnt(4)" ::: "memory");
    } else {
      asm volatile("s_waitcnt vmcnt(0)" ::: "memory");
    }
    __builtin_amdgcn_s_barrier();
    asm volatile("" ::: "memory");

    const ushort_t* pa = &lA[cur][0] + aoff;
    const ushort_t* pb = &lB[cur][0] + boff;
    short8 aF[4], bF[4];
#pragma unroll
    for (int m2 = 0; m2 < 4; ++m2) aF[m2] = *(const short8*)(pa + m2 * 16 * 32);
#pragma unroll
    for (int n2 = 0; n2 < 4; ++n2) bF[n2] = *(const short8*)(pb + n2 * 16 * 32);
#pragma unroll
    for (int m2 = 0; m2 < 4; ++m2)
#pragma unroll
      for (int n2 = 0; n2 < 4; ++n2)
        acc[m2][n2] = __builtin_amdgcn_mfma_f32_16x16x32_bf16(
            aF[m2], bF[n2], acc[m2][n2], 0, 0, 0);
    __builtin_amdgcn_s_barrier();
    asm volatile("" ::: "memory");
  }

  const int layer = idxg[tm >> 9];
  const int rowBase = layer * N_TOK + (tm & (N_TOK - 1));

#pragma unroll
  for (int m2 = 0; m2 < 4; ++m2) {
#pragma unroll
    for (int n2 = 0; n2 < 4; ++n2) {
      const int colg = tn + wc * 64 + n2 * 16 + (lane & 15);
      const float bv = bias[colg];
#pragma unroll
      for (int r = 0; r < 4; ++r) {
        const int rowl = wr * 64 + m2 * 16 + (lane >> 4) * 4 + r;
        const float v = acc[m2][n2][r];
        const int grow = rowBase + rowl;
        if (colg < INTER) {
          float h = v + bv;
          h = h / (1.f + expf(-h));
          hidden[(size_t)grow * INTER + colg] = f2bf(h);
        } else {
          outp[(size_t)grow * EMBED + (colg - INTER)] = v + bv;
        }
      }
    }
  }
}

// ---- phase-2: 256x256x(K/2) 8-phase MFMA GEMM --------------------------
// Identical schedule/ledger to R4, but ALL global_load_lds use offset=0
// (pointer advances mid-iteration supply the K-tile stepping), every
// s_barrier is followed by a zero-cost compiler memory fence, and every
// counted vmcnt is followed by sched_barrier(0).
// Ledger (steady state, per iter t; 2 loads per STG per wave):
//   entry invariant: outstanding = [KT(2t+1).A0(2), B0(2)]
//   ph1: stage KT(2t+1).A1,B1 -> buf1; ADV (ptr->KT(2t+2))
//   ph3: stage KT(2t+2).A0 -> buf0
//   ph4: stage KT(2t+2).B0 -> buf0 ; vmcnt(8) drains KT(2t+1).A0,B0
//   ph5: stage KT(2t+2).A1,B1 -> buf0; ADV ; vmcnt(8) drains KT(2t+1).A1,B1
//   ph7: stage KT(2t+3).A0 -> buf1
//   ph8: stage KT(2t+3).B0 -> buf1 ; vmcnt(4) drains all KT(2t+2)
#define RA0 0
#define RA1 16384
#define RB0 32768
#define RB1 49152
#define BUF1 65536

__global__ __launch_bounds__(512, 2)
void gemm256k(const ushort_t* __restrict__ A, const ushort_t* __restrict__ Bw,
              const float* __restrict__ bias, float* __restrict__ outp) {
  __shared__ __align__(16) char smem[131072];
  const int tid = threadIdx.x;
  const int w = tid >> 6, l = tid & 63;

  const int L = blockIdx.x;
  const int xcd = L & 7, j = L >> 3;
  const int nt = j & 3, kh = (j >> 2) & 1, mtl = j >> 3;
  const int mt = xcd * 12 + mtl;
  const int tm = mt * 256, tn = nt * 256;
  const int kbase = kh * 2048;

  // staging source pointers (pre-swizzled global, linear LDS dest)
  const ushort_t* pA0[2]; const ushort_t* pA1[2];
  const ushort_t* pB0[2]; const ushort_t* pB1[2];
  int dstq[2];
#pragma unroll
  for (int jj = 0; jj < 2; ++jj) {
    const int q = w * 2 + jj;                 // 0..15
    const int ks = q >> 3;
    const int hr = (q & 7) * 16 + (l >> 2);   // HT row 0..127
    const int c = (l & 3) ^ ((hr >> 1) & 3);  // source chunk (inverse swz)
    const int koff = ks * 32 + c * 8;
    pA0[jj] = A + (size_t)(tm + hr) * 4096 + kbase + koff;
    pA1[jj] = A + (size_t)(tm + 128 + hr) * 4096 + kbase + koff;
    pB0[jj] = Bw + (size_t)(tn + hr) * 4096 + kbase + koff;
    pB1[jj] = Bw + (size_t)(tn + 128 + hr) * 4096 + kbase + koff;
    dstq[jj] = q * 1024;                      // wave-uniform LDS byte base
  }

#define STG(P, R) do { \
    gld_lds16(P[0], smem + (R) + dstq[0]); \
    gld_lds16(P[1], smem + (R) + dstq[1]); } while (0)
#define ADV() do { _Pragma("unroll") for (int jj = 0; jj < 2; ++jj) { \
    pA0[jj] += 64; pA1[jj] += 64; pB0[jj] += 64; pB1[jj] += 64; } } while (0)

  // fragment read bases (swizzled read, conflict-free)
  const int wr = w >> 2, wc = w & 3;          // 2M x 4N waves
  const int xl = ((l & 15) >> 1) & 3;
  const int aRd = (wr * 64 + (l & 15)) * 64 + (((l >> 4) ^ xl) * 16);
  const int bRd = (wc * 32 + (l & 15)) * 64 + (((l >> 4) ^ xl) * 16);

  f32x4 acc[8][4];
  const f32x4 zero = {0.f, 0.f, 0.f, 0.f};
#pragma unroll
  for (int m = 0; m < 8; ++m)
#pragma unroll
    for (int n = 0; n < 4; ++n) acc[m][n] = zero;
  short8 aF[4][2], bF0[2][2], bF1[2][2];

#define LDA8(BUF, MH) do { _Pragma("unroll") for (int mp = 0; mp < 4; ++mp) { \
    _Pragma("unroll") for (int ks = 0; ks < 2; ++ks) \
      aF[mp][ks] = *(const short8*)(smem + (BUF)*65536 + (MH)*16384 + ks*8192 + mp*1024 + aRd); } } while (0)
#define LDB4(D, BUF, NH) do { _Pragma("unroll") for (int np = 0; np < 2; ++np) { \
    _Pragma("unroll") for (int ks = 0; ks < 2; ++ks) \
      D[np][ks] = *(const short8*)(smem + (BUF)*65536 + 32768 + (NH)*16384 + ks*8192 + np*1024 + bRd); } } while (0)
#define QMFMA(MH, NH, BF) do { _Pragma("unroll") for (int mp = 0; mp < 4; ++mp) { \
    _Pragma("unroll") for (int np = 0; np < 2; ++np) { \
      _Pragma("unroll") for (int ks = 0; ks < 2; ++ks) \
        acc[(MH)*4+mp][(NH)*2+np] = __builtin_amdgcn_mfma_f32_16x16x32_bf16( \
            aF[mp][ks], BF[np][ks], acc[(MH)*4+mp][(NH)*2+np], 0, 0, 0); } } } while (0)
#define BARRF do { __builtin_amdgcn_s_barrier(); asm volatile("" ::: "memory"); } while (0)
#define WAITV(N) do { asm volatile("s_waitcnt vmcnt(" #N ")" ::: "memory"); \
    __builtin_amdgcn_sched_barrier(0); } while (0)
#define PRIO1 __builtin_amdgcn_s_setprio(1)
#define PRIO0 __builtin_amdgcn_s_setprio(0)

  // prologue: KT0 (4 HTs -> buf0); ADV; KT1.A0,B0 -> buf1
  STG(pA0, RA0);
  STG(pA1, RA1);
  STG(pB0, RB0);
  STG(pB1, RB1);
  ADV();                                      // ptr -> KT1
  STG(pA0, BUF1 + RA0);
  STG(pB0, BUF1 + RB0);
  WAITV(4);                                   // KT0 landed
  BARRF;

  const int nit = 16;                          // 32 K-tiles per k-half
  for (int t = 0; t < nit; ++t) {
    const bool more = (t + 1 < nit);
    // ph1: Q(0,0) on buf0                     (entry: ptr = KT(2t+1))
    LDA8(0, 0);
    LDB4(bF0, 0, 0);
    STG(pA1, BUF1 + RA1);                      // KT(2t+1).A1
    STG(pB1, BUF1 + RB1);                      // KT(2t+1).B1
    ADV();                                     // ptr -> KT(2t+2)
    BARRF; PRIO1; QMFMA(0, 0, bF0); PRIO0; BARRF;
    // ph2: Q(0,1)
    LDB4(bF1, 0, 1);
    BARRF; PRIO1; QMFMA(0, 1, bF1); PRIO0; BARRF;
    // ph3: Q(1,0)
    LDA8(0, 1);
    if (more) STG(pA0, RA0);                   // KT(2t+2).A0
    BARRF; PRIO1; QMFMA(1, 0, bF0); PRIO0; BARRF;
    // ph4: Q(1,1)
    if (more) { STG(pB0, RB0); WAITV(8); }     // KT(2t+2).B0
    else      { WAITV(4); }
    BARRF; PRIO1; QMFMA(1, 1, bF1); PRIO0; BARRF;
    // ph5: Q(0,0) on buf1
    LDA8(1, 0);
    LDB4(bF0, 1, 0);
    if (more) { STG(pA1, RA1); STG(pB1, RB1); ADV(); WAITV(8); }  // KT(2t+2).A1,B1; ptr->KT(2t+3)
    else      { WAITV(0); }
    BARRF; PRIO1; QMFMA(0, 0, bF0); PRIO0; BARRF;
    // ph6: Q(0,1)
    LDB4(bF1, 1, 1);
    BARRF; PRIO1; QMFMA(0, 1, bF1); PRIO0; BARRF;
    // ph7: Q(1,0)
    LDA8(1, 1);
    if (more) STG(pA0, BUF1 + RA0);            // KT(2t+3).A0
    BARRF; PRIO1; QMFMA(1, 0, bF0); PRIO0; BARRF;
    // ph8: Q(1,1)
    if (more) { STG(pB0, BUF1 + RB0); WAITV(4); }  // KT(2t+3).B0
    else      { WAITV(0); }
    BARRF; PRIO1; QMFMA(1, 1, bF1); PRIO0; BARRF;
  }

  // epilogue: out += acc (+ bias once) via f32 atomics
  const float bmul = (kh == 0) ? 1.0f : 0.0f;
  float bv[4];
#pragma unroll
  for (int n = 0; n < 4; ++n)
    bv[n] = bmul * bias[tn + (n >> 1) * 128 + wc * 32 + (n & 1) * 16 + (l & 15)];
#pragma unroll
  for (int m = 0; m < 8; ++m) {
    const int row = tm + (m >> 2) * 128 + wr * 64 + (m & 3) * 16 + (l >> 4) * 4;
#pragma unroll
    for (int n = 0; n < 4; ++n) {
      const int col = tn + (n >> 1) * 128 + wc * 32 + (n & 1) * 16 + (l & 15);
      float* po = outp + (size_t)row * EMBED + col;
#pragma unroll
      for (int ri = 0; ri < 4; ++ri)
        atomicAdd(po + (size_t)ri * EMBED, acc[m][n][ri] + bv[n]);
    }
  }
}

// ---- launch -------------------------------------------------------------

extern "C" void kernel_launch(void* const* d_in, const int* in_sizes, int n_in,
                              void* d_out, int out_size, void* d_ws, size_t ws_size,
                              hipStream_t stream) {
  const float* xg[3] = {(const float*)d_in[0], (const float*)d_in[3], (const float*)d_in[6]};
  const float* mg[3] = {(const float*)d_in[1], (const float*)d_in[4], (const float*)d_in[7]};
  const float* tg[3] = {(const float*)d_in[2], (const float*)d_in[5], (const float*)d_in[8]};
  const int* idxg[3] = {(const int*)d_in[9], (const int*)d_in[10], (const int*)d_in[11]};
  const float* W_lin = (const float*)d_in[12];
  const float* b_lin = (const float*)d_in[13];
  const float* W_res = (const float*)d_in[14];
  const float* b_res = (const float*)d_in[15];
  const float* W_out = (const float*)d_in[16];
  const float* b_out = (const float*)d_in[17];
  float* out = (float*)d_out;

  char* ws = (char*)d_ws;
  size_t off = 0;
  auto alloc = [&](size_t b) -> char* {
    size_t o = (off + 255) & ~(size_t)255;
    off = o + b;
    return ws + o;
  };

  ushort_t* hidden = (ushort_t*)alloc((size_t)MROWS * INTER * 2);   // 201 MB
  const int Ps[3] = {16, 32, 64};
  const int Kp[3] = {64, 96, 192};
  ushort_t* xsw[3];
  ushort_t* wcat[3];
  for (int g = 0; g < 3; ++g) xsw[g]  = (ushort_t*)alloc((size_t)8192 * Kp[g] * 2);
  for (int g = 0; g < 3; ++g) wcat[g] = (ushort_t*)alloc((size_t)NCAT * Kp[g] * 2);
  ushort_t* wout = (ushort_t*)alloc((size_t)EMBED * INTER * 2);     // 8 MB
  float* bcat = (float*)alloc((size_t)NCAT * 4);

  prep_bcat<<<(NCAT + 255) / 256, 256, 0, stream>>>(b_lin, b_res, bcat);
  prep_wout<<<(EMBED * INTER) / 256, 256, 0, stream>>>(W_out, wout);
  for (int g = 0; g < 3; ++g) {
    int tw = NCAT * Kp[g];
    prep_wcat<<<(tw + 255) / 256, 256, 0, stream>>>(W_lin, W_res, wcat[g], 3 * Ps[g], Kp[g]);
    int tx = 8192 * Kp[g];
    prep_xs<<<(tx + 255) / 256, 256, 0, stream>>>(xg[g], mg[g], tg[g], xsw[g], Ps[g], Kp[g]);
  }
  // phase 1: per group, [8192 x Kp] @ [5120 x Kp]^T
  for (int g = 0; g < 3; ++g)
    gemm128p1<<<dim3(64, 40), 256, 0, stream>>>(xsw[g], wcat[g], Kp[g], bcat,
                                                hidden, out, idxg[g]);
  // phase 2: [24576 x 4096] @ [1024 x 4096]^T, K-split=2, out += acc (+b_out)
  gemm256k<<<dim3(768), 512, 0, stream>>>(hidden, wout, b_out, out);
}